// Round 3
// baseline (1577.051 us; speedup 1.0000x reference)
//
#include <hip/hip_runtime.h>

#define HID 512
#define TSTEPS 1000
#define NB 128
#define NIN 5
#define NOUT 2

// Transpose w_rec[h][j] -> wT[j][h]; row j=512 is all zeros (gather padding target).
// Re-run every launch: harness re-poisons d_ws before each timed call.
__global__ void snn_prep(const float* __restrict__ w_rec, float* __restrict__ wT) {
  int idx = blockIdx.x * 256 + threadIdx.x;
  if (idx < (HID + 1) * HID) {
    int j = idx >> 9;          // 0..512
    int h = idx & (HID - 1);
    wT[idx] = (j < HID) ? w_rec[h * HID + j] : 0.0f;
  }
}

// One workgroup per batch; thread = hidden unit h. Whole T-loop inside the kernel,
// only __syncthreads() between steps (batches independent -> no grid sync).
// Per step: issue spike-column loads first (<=64 in flight), overlap with all
// spike/ballot/readout work (z_t does NOT depend on this step's gather), then
// consume in strictly ascending-j order (bit-exact vs dense ascending FMA chain).
__global__ __launch_bounds__(HID) void snn_main(
    const float* __restrict__ x,      // [T][B][5]
    const float* __restrict__ w_in,   // [H][5]
    const float* __restrict__ w_out,  // [2][H]
    const float* __restrict__ wT,     // [513][H]
    float* __restrict__ out)          // [T][B][2]
{
#pragma clang fp contract(off)
  const int b = blockIdx.x;
  const int tid = threadIdx.x;
  const int lane = tid & 63;
  const int wv = tid >> 6;

  __shared__ unsigned long long s_mask[8];
  __shared__ int __align__(16) s_list[HID + 32];   // 16B-aligned: read via ds_read_b128
  __shared__ float s_y[16];          // [o][wave]
  __shared__ float s_x[2][8];        // double-buffered x_t (5 used)

  // Per-thread weights (resident for the whole run)
  const float win0 = w_in[tid * NIN + 0];
  const float win1 = w_in[tid * NIN + 1];
  const float win2 = w_in[tid * NIN + 2];
  const float win3 = w_in[tid * NIN + 3];
  const float win4 = w_in[tid * NIN + 4];
  const float wo0 = w_out[tid];
  const float wo1 = w_out[HID + tid];

  // State
  float v = 0.0f, cur = 0.0f;        // LIF membrane, synaptic current
  float vo = 0.0f, io = 0.0f;        // LI readout (only tid<2 use)

  if (tid < NIN) s_x[0][tid] = x[b * NIN + tid];
  __syncthreads();

  int total = 0;                     // padded spike count of z_{t-1} (uniform)

  for (int t = 0; t < TSTEPS; ++t) {
    // ---------- phase 1: issue recurrent gather (list of z_{t-1}) ----------
    float racc = 0.0f;
    int n = 0;
    // streamed surplus batches (only when >64 spikes): issue+consume, ascending
    for (; n + 64 < total; n += 32) {
      int idxs[32];
#pragma unroll
      for (int q = 0; q < 8; ++q) {
        int4 jv = *reinterpret_cast<const int4*>(&s_list[n + 4 * q]);
        idxs[4 * q + 0] = jv.x; idxs[4 * q + 1] = jv.y;
        idxs[4 * q + 2] = jv.z; idxs[4 * q + 3] = jv.w;
      }
      float wbuf[32];
#pragma unroll
      for (int k = 0; k < 32; ++k) wbuf[k] = wT[idxs[k] * HID + tid];
#pragma unroll
      for (int k = 0; k < 32; ++k) racc = __fadd_rn(racc, wbuf[k]);
    }
    const bool hasA = (n < total);
    const bool hasB = (n + 32 < total);
    float wbufA[32], wbufB[32];
    if (hasA) {
      int idxs[32];
#pragma unroll
      for (int q = 0; q < 8; ++q) {
        int4 jv = *reinterpret_cast<const int4*>(&s_list[n + 4 * q]);
        idxs[4 * q + 0] = jv.x; idxs[4 * q + 1] = jv.y;
        idxs[4 * q + 2] = jv.z; idxs[4 * q + 3] = jv.w;
      }
#pragma unroll
      for (int k = 0; k < 32; ++k) wbufA[k] = wT[idxs[k] * HID + tid];
    }
    if (hasB) {
      int idxs[32];
#pragma unroll
      for (int q = 0; q < 8; ++q) {
        int4 jv = *reinterpret_cast<const int4*>(&s_list[n + 32 + 4 * q]);
        idxs[4 * q + 0] = jv.x; idxs[4 * q + 1] = jv.y;
        idxs[4 * q + 2] = jv.z; idxs[4 * q + 3] = jv.w;
      }
#pragma unroll
      for (int k = 0; k < 32; ++k) wbufB[k] = wT[idxs[k] * HID + tid];
    }

    // ---------- phase 2: independent work (overlaps load latency) ----------
    const float* sx = s_x[t & 1];
    float a = __fmul_rn(sx[0], win0);      // == fma(x0,w0,0): ascending-k chain
    a = fmaf(sx[1], win1, a);
    a = fmaf(sx[2], win2, a);
    a = fmaf(sx[3], win3, a);
    a = fmaf(sx[4], win4, a);

    const float vd = __fadd_rn(v, __fmul_rn(0.1f, __fsub_rn(cur, v)));  // old cur!
    const bool spike = vd > 1.0f;
    v = spike ? 0.0f : vd;

    float r0 = spike ? wo0 : 0.0f;         // readout partials (feed-forward path)
    float r1 = spike ? wo1 : 0.0f;
#pragma unroll
    for (int off = 1; off < 64; off <<= 1) {
      r0 = __fadd_rn(r0, __shfl_xor(r0, off, 64));
      r1 = __fadd_rn(r1, __shfl_xor(r1, off, 64));
    }
    const unsigned long long m = __ballot(spike);
    if (lane == 0) { s_mask[wv] = m; s_y[wv] = r0; s_y[8 + wv] = r1; }
    if (t + 1 < TSTEPS && tid < NIN)
      s_x[(t + 1) & 1][tid] = x[(size_t)(t + 1) * NB * NIN + b * NIN + tid];

    // ---------- phase 3: consume gather, update synaptic current ----------
    if (hasA) {
#pragma unroll
      for (int k = 0; k < 32; ++k) racc = __fadd_rn(racc, wbufA[k]);
    }
    if (hasB) {
#pragma unroll
      for (int k = 0; k < 32; ++k) racc = __fadd_rn(racc, wbufB[k]);
    }
    cur = __fadd_rn(__fmul_rn(0.8f, cur), __fadd_rn(a, racc));

    __syncthreads();   // SYNC1: masks, s_y, s_x visible

    // ---------- phase 4: list build + LI readout ----------
    int base = 0, tot = 0;
#pragma unroll
    for (int w2 = 0; w2 < 8; ++w2) {
      const int c = __popcll(s_mask[w2]);
      base += (w2 < wv) ? c : 0;
      tot += c;
    }
    if (spike) {
      const int pos = base + __popcll(m & ((1ull << lane) - 1ull));
      s_list[pos] = tid;
    }
    const int padded = (tot + 31) & ~31;
    if (tid >= tot && tid < padded) s_list[tid] = HID;  // zero-row pad

    if (tid < NOUT) {
      float y = 0.0f;
#pragma unroll
      for (int w2 = 0; w2 < 8; ++w2) y = __fadd_rn(y, s_y[tid * 8 + w2]);
      // vo_new uses OLD io; out[t]=vo_new; io_new uses y of current z
      const float von = __fadd_rn(vo, __fmul_rn(0.1f, __fsub_rn(io, vo)));
      io = __fadd_rn(__fmul_rn(0.8f, io), y);
      vo = von;
      out[(size_t)t * NB * NOUT + b * NOUT + tid] = von;
    }

    __syncthreads();   // SYNC2: list_t complete before next step's gather
    total = padded;
  }
}

extern "C" void kernel_launch(void* const* d_in, const int* in_sizes, int n_in,
                              void* d_out, int out_size, void* d_ws, size_t ws_size,
                              hipStream_t stream) {
  const float* x     = (const float*)d_in[0];
  const float* w_in  = (const float*)d_in[1];
  const float* w_rec = (const float*)d_in[2];
  const float* w_out = (const float*)d_in[3];
  float* out = (float*)d_out;
  float* wT = (float*)d_ws;  // (HID+1)*HID floats ~= 1.05 MB of workspace

  const int prep_elems = (HID + 1) * HID;
  snn_prep<<<(prep_elems + 255) / 256, 256, 0, stream>>>(w_rec, wT);
  snn_main<<<NB, HID, 0, stream>>>(x, w_in, w_out, wT, out);
}

// Round 5
// 1402.463 us; speedup vs baseline: 1.1245x; 1.1245x over previous
//
#include <hip/hip_runtime.h>

#define HID 512
#define TSTEPS 1000
#define NB 128
#define NIN 5
#define NOUT 2
#define ROWW 516                   // wT2 row: 512 w_rec cols + y0 + y1 + 2 pad
#define ROWB (ROWW * 4)            // 2064 bytes/row (8B aligned)
#define DUMMYOFF (HID * ROWB)      // byte offset of the all-zeros row (j=512)

// Build wT2[j][h]: h<512 -> w_rec[h][j]; h=512/513 -> w_out[h-512][j]; else 0.
// Row j=512 is all zeros (padding target). Re-run every launch (ws re-poisoned).
__global__ void snn_prep(const float* __restrict__ w_rec,
                         const float* __restrict__ w_out,
                         float* __restrict__ wT2) {
  int idx = blockIdx.x * 256 + threadIdx.x;
  const int total = (HID + 1) * ROWW;
  if (idx >= total) return;
  int j = idx / ROWW;
  int h = idx - j * ROWW;
  float v = 0.0f;
  if (j < HID) {
    if (h < HID) v = w_rec[h * HID + j];
    else if (h < HID + NOUT) v = w_out[(h - HID) * HID + j];
  }
  wT2[idx] = v;
}

// 320 threads = 5 waves. tid<256: units 2t,2t+1. tid==256: readout (y cols 512/513).
// One barrier per step; double-buffered per-wave spike segments (byte row-offsets,
// padded to x4 with the zero row -> exact no-op adds, order = ascending j).
__global__ __launch_bounds__(320) void snn_main(
    const float* __restrict__ x,      // [T][B][5]
    const float* __restrict__ w_in,   // [H][5]
    const float* __restrict__ wT2,    // [513][516]
    float* __restrict__ out)          // [T][B][2]
{
#pragma clang fp contract(off)
  const int b = blockIdx.x;
  const int tid = threadIdx.x;
  const int lane = tid & 63;
  const int wv = tid >> 6;            // 0..4
  const int h0 = tid * 2;             // 512 for the readout lane

  __shared__ int __align__(16) s_seg[2][4][132];   // [buf][wave][padded entries]
  __shared__ unsigned int s_pcnt[2];               // 4 packed u8 padded counts

  // per-unit input weights
  float wi00 = 0, wi01 = 0, wi02 = 0, wi03 = 0, wi04 = 0;
  float wi10 = 0, wi11 = 0, wi12 = 0, wi13 = 0, wi14 = 0;
  if (tid < 256) {
    const float* wa = w_in + h0 * NIN;
    wi00 = wa[0]; wi01 = wa[1]; wi02 = wa[2]; wi03 = wa[3]; wi04 = wa[4];
    const float* wb = w_in + (h0 + 1) * NIN;
    wi10 = wb[0]; wi11 = wb[1]; wi12 = wb[2]; wi13 = wb[3]; wi14 = wb[4];
  }

  // state
  float v0 = 0, v1 = 0, c0 = 0, c1 = 0;            // LIF pairs
  float io0 = 0, io1 = 0, vo0 = 0, vo1 = 0;        // LI readout (lane 256)
  float pend0 = 0, pend1 = 0;

  // x_0
  float xr0, xr1, xr2, xr3, xr4;
  {
    const float* xp = x + (size_t)b * NIN;
    xr0 = xp[0]; xr1 = xp[1]; xr2 = xp[2]; xr3 = xp[3]; xr4 = xp[4];
  }

  if (tid == 0) s_pcnt[0] = 0;
  __syncthreads();

  const char* wtb = (const char*)wT2 + (size_t)h0 * 4;

  for (int t = 0; t < TSTEPS; ++t) {
    const int rb = t & 1, wbuf = rb ^ 1;

    // deferred out store (drains during this step's gather)
    if (tid == 256 && t > 0) {
      float2 po; po.x = pend0; po.y = pend1;
      *(float2*)(out + (size_t)(t - 1) * NB * NOUT + b * NOUT) = po;
    }

    // prefetch x_{t+1} (uniform address -> scalar loads)
    float nx0, nx1, nx2, nx3, nx4;
    {
      const int tn = (t + 1 < TSTEPS) ? t + 1 : t;
      const float* xp = x + ((size_t)tn * NB + b) * NIN;
      nx0 = xp[0]; nx1 = xp[1]; nx2 = xp[2]; nx3 = xp[3]; nx4 = xp[4];
    }

    // padded per-wave counts of z_{t-1}
    const unsigned int pw = s_pcnt[rb];
    int pc0 = __builtin_amdgcn_readfirstlane((int)(pw & 255u));
    int pc1 = __builtin_amdgcn_readfirstlane((int)((pw >> 8) & 255u));
    int pc2 = __builtin_amdgcn_readfirstlane((int)((pw >> 16) & 255u));
    int pc3 = __builtin_amdgcn_readfirstlane((int)((pw >> 24) & 255u));
    const int b1 = pc0, b2v = b1 + pc1, b3v = b2v + pc2;
    const int tot = b3v + pc3;
    const int ng = tot >> 2;   // groups of 4 entries

    float racc0 = 0.0f, racc1 = 0.0f;
    if (h0 < HID + NOUT) {
      const char* segbase = (const char*)&s_seg[rb][0][0];

#define SEGADDR(GI, AP) { int w_ = 0, bw_ = 0;                         \
      if ((GI) >= b1)  { w_ = 1; bw_ = b1;  }                          \
      if ((GI) >= b2v) { w_ = 2; bw_ = b2v; }                          \
      if ((GI) >= b3v) { w_ = 3; bw_ = b3v; }                          \
      AP = segbase + w_ * 528 + ((GI) - bw_) * 4; }
#define STAGE(JJ, F0, F1, F2, F3, G) { const char* ap_;                \
      SEGADDR((G) * 4, ap_);                                           \
      JJ = *(const int4*)ap_;                                          \
      F0 = *(const float2*)(wtb + JJ.x);                               \
      F1 = *(const float2*)(wtb + JJ.y);                               \
      F2 = *(const float2*)(wtb + JJ.z);                               \
      F3 = *(const float2*)(wtb + JJ.w); }
#define CONSUME(F0, F1, F2, F3) {                                      \
      racc0 = __fadd_rn(racc0, F0.x); racc1 = __fadd_rn(racc1, F0.y);  \
      racc0 = __fadd_rn(racc0, F1.x); racc1 = __fadd_rn(racc1, F1.y);  \
      racc0 = __fadd_rn(racc0, F2.x); racc1 = __fadd_rn(racc1, F2.y);  \
      racc0 = __fadd_rn(racc0, F3.x); racc1 = __fadd_rn(racc1, F3.y); }

      if (ng > 0) {
        int4 jA, jB;
        float2 a0, a1, a2, a3, q0, q1, q2, q3;
        STAGE(jA, a0, a1, a2, a3, 0);
        int g = 1;
        for (; g + 1 < ng; g += 2) {
          STAGE(jB, q0, q1, q2, q3, g);
          CONSUME(a0, a1, a2, a3);
          STAGE(jA, a0, a1, a2, a3, g + 1);
          CONSUME(q0, q1, q2, q3);
        }
        if (g < ng) {
          STAGE(jB, q0, q1, q2, q3, g);
          CONSUME(a0, a1, a2, a3);
          CONSUME(q0, q1, q2, q3);
        } else {
          CONSUME(a0, a1, a2, a3);
        }
      }
    }

    if (tid < 256) {
      // input currents (ascending-k chain, identical ops to prior round)
      float a0 = __fmul_rn(xr0, wi00);
      a0 = fmaf(xr1, wi01, a0); a0 = fmaf(xr2, wi02, a0);
      a0 = fmaf(xr3, wi03, a0); a0 = fmaf(xr4, wi04, a0);
      float a1 = __fmul_rn(xr0, wi10);
      a1 = fmaf(xr1, wi11, a1); a1 = fmaf(xr2, wi12, a1);
      a1 = fmaf(xr3, wi13, a1); a1 = fmaf(xr4, wi14, a1);

      const float vd0 = __fadd_rn(v0, __fmul_rn(0.1f, __fsub_rn(c0, v0)));
      const float vd1 = __fadd_rn(v1, __fmul_rn(0.1f, __fsub_rn(c1, v1)));
      const bool s0 = vd0 > 1.0f;
      const bool s1 = vd1 > 1.0f;
      v0 = s0 ? 0.0f : vd0;
      v1 = s1 ? 0.0f : vd1;
      c0 = __fadd_rn(__fmul_rn(0.8f, c0), __fadd_rn(a0, racc0));
      c1 = __fadd_rn(__fmul_rn(0.8f, c1), __fadd_rn(a1, racc1));

      // publish spikes: per-wave segment, ascending j = 2*lane+parity
      const unsigned long long me = __ballot(s0);
      const unsigned long long mo = __ballot(s1);
      const unsigned long long below = (1ull << lane) - 1ull;
      const int cb = __popcll(me & below) + __popcll(mo & below);
      const int cnt = __popcll(me) + __popcll(mo);
      const int pcw = (cnt + 3) & ~3;
      int* seg = &s_seg[wbuf][wv][0];
      if (s0) seg[cb] = h0 * ROWB;
      if (s1) seg[cb + (s0 ? 1 : 0)] = (h0 + 1) * ROWB;
      if (lane < pcw - cnt) seg[cnt + lane] = DUMMYOFF;
      if (lane == 0) ((unsigned char*)&s_pcnt[wbuf])[wv] = (unsigned char)pcw;
    } else if (tid == 256) {
      // racc = y_{t-1}; finish io_{t-1}, then vo_t (uses io_{t-1}) -> out[t]
      io0 = __fadd_rn(__fmul_rn(0.8f, io0), racc0);
      io1 = __fadd_rn(__fmul_rn(0.8f, io1), racc1);
      vo0 = __fadd_rn(vo0, __fmul_rn(0.1f, __fsub_rn(io0, vo0)));
      vo1 = __fadd_rn(vo1, __fmul_rn(0.1f, __fsub_rn(io1, vo1)));
      pend0 = vo0; pend1 = vo1;
    }

    xr0 = nx0; xr1 = nx1; xr2 = nx2; xr3 = nx3; xr4 = nx4;
    __syncthreads();   // single barrier: step t's segment visible for t+1
  }

  if (tid == 256) {
    float2 po; po.x = pend0; po.y = pend1;
    *(float2*)(out + (size_t)(TSTEPS - 1) * NB * NOUT + b * NOUT) = po;
  }
}

extern "C" void kernel_launch(void* const* d_in, const int* in_sizes, int n_in,
                              void* d_out, int out_size, void* d_ws, size_t ws_size,
                              hipStream_t stream) {
  const float* x     = (const float*)d_in[0];
  const float* w_in  = (const float*)d_in[1];
  const float* w_rec = (const float*)d_in[2];
  const float* w_out = (const float*)d_in[3];
  float* out = (float*)d_out;
  float* wT2 = (float*)d_ws;   // (513*516)*4 ~= 1.06 MB

  const int prep_elems = (HID + 1) * ROWW;
  snn_prep<<<(prep_elems + 255) / 256, 256, 0, stream>>>(w_rec, w_out, wT2);
  snn_main<<<NB, 320, 0, stream>>>(x, w_in, wT2, out);
}